// Round 12
// baseline (1781.876 us; speedup 1.0000x reference)
//
#include <hip/hip_runtime.h>

#define BB 4
#define SS 512
#define DD 768
#define HH 12
#define NLAYER 2
#define EE 8
#define DFF 3072
#define TT 2048
#define CAP 320
#define HD 64

typedef unsigned short u16;
typedef long long ll;
typedef _Float16 f16x8 __attribute__((ext_vector_type(8)));
typedef float f32x4 __attribute__((ext_vector_type(4)));

union F16U { _Float16 h; u16 u; };

// fp16 two-term split: v = h0 + h1*2^-12 + err, |err| <= ~2^-24*|v|.
__device__ __forceinline__ void split2h(float v, u16& h0, u16& h1) {
    F16U c0; c0.h = (_Float16)v;
    float r = (v - (float)c0.h) * 4096.0f;
    F16U c1; c1.h = (_Float16)r;
    h0 = c0.u; h1 = c1.u;
}
__device__ __forceinline__ float rec2h(u16 a, u16 b) {
    F16U c0, c1; c0.u = a; c1.u = b;
    return (float)c0.h + (float)c1.h * (1.0f / 4096.0f);
}

#define MFMA16(a, b, c) __builtin_amdgcn_mfma_f32_16x16x32_f16(a, b, c, 0, 0, 0)

// ---------------- GEMM (BK=64) ----------------
struct GemmP {
    const u16* A = nullptr; ll sAp = 0;
    const void* B = nullptr; ll sBp = 0;
    const float* bias = nullptr; ll biasStride = 0;
    void* C = nullptr; ll sCp = 0;
    int M = 0, N = 0, K = 0, lda = 0, ldb = 0, ldc = 0;
    int modA = 1; ll sA1 = 0, sA2 = 0;
    int modB = 1; ll sB1 = 0, sB2 = 0;
    int modC = 1; ll sC1 = 0, sC2 = 0;
    float alpha = 1.f;
    int flags = 0;    // 1=bias 2=relu 8=planes-out 16=partial-out(split-K)
    int KS = 1; ll partStride = 0;
    int Jc = 1;       // XCD supertile chunk (must divide gridDim.y*gridDim.z)
};

#define BK 64
#define PADK 72   // 144B rows: 16B-aligned (b128 ok)

template<bool BTRANS, int NS>
__global__ __launch_bounds__(256) void gemm_kernel(GemmP p) {
    __shared__ u16 Al[NS][128][PADK];
    __shared__ u16 Bl[NS][128][PADK];
    const int tid = threadIdx.x;

    // ---- XCD supertile remap ----
    int bx, by, bz;
    {
        int gx = gridDim.x, gy = gridDim.y;
        int NBt = gx * gy * gridDim.z;
        int L = blockIdx.x + gx * (blockIdx.y + gy * blockIdx.z);
        int q = NBt >> 3, r = NBt & 7;
        int xcd = L & 7, wi = L >> 3;
        int c = (xcd < r) ? xcd * (q + 1) + wi : r * (q + 1) + (xcd - r) * q + wi;
        int Jc = p.Jc;
        int gxJ = gx * Jc;
        int sj = c / gxJ;
        int t = c - sj * gxJ;
        bx = t / Jc;
        int j = sj * Jc + (t - (t / Jc) * Jc);
        by = j % gy; bz = j / gy;
    }
    const int n0 = bx * 128, m0 = by * 128;
    const int slice = bz % p.KS;
    const int z = bz / p.KS;
    const int kslice = p.K / p.KS;
    const int k0 = slice * kslice;
    const int nkt = kslice >> 6;

    const u16* Ap = p.A + (ll)(z % p.modA) * p.sA1 + (ll)(z / p.modA) * p.sA2 + k0;
    const ll zB = (ll)(z % p.modB) * p.sB1 + (ll)(z / p.modB) * p.sB2;
    const ll zC = (ll)(z % p.modC) * p.sC1 + (ll)(z / p.modC) * p.sC2;
    const u16* Bpu = BTRANS ? ((const u16*)p.B + zB + k0) : nullptr;
    const float* Bpf = BTRANS ? nullptr : ((const float*)p.B + zB);

    const int lane = tid & 63, wid = tid >> 6;
    const int wm = (wid >> 1) * 64, wn = (wid & 1) * 64;
    const int ar = lane & 15, kg = (lane >> 4) * 8;

    f32x4 acc0[4][4] = {};
    f32x4 acc1[4][4] = {};

    uint4 ra[4 * NS];
    uint4 rb[4 * NS];

    auto loadA = [&](int kt) {
        #pragma unroll
        for (int s = 0; s < NS; ++s)
            #pragma unroll
            for (int h = 0; h < 4; ++h) {
                int c = tid + h * 256, row = c >> 3, q = c & 7;
                int gm = m0 + row;
                uint4 v = {0u, 0u, 0u, 0u};
                if (gm < p.M) v = *(const uint4*)(Ap + (ll)s * p.sAp + (size_t)gm * p.lda + kt * BK + q * 8);
                ra[s * 4 + h] = v;
            }
    };
    auto storeA = [&]() {
        #pragma unroll
        for (int s = 0; s < NS; ++s)
            #pragma unroll
            for (int h = 0; h < 4; ++h) {
                int c = tid + h * 256, row = c >> 3, q = c & 7;
                *(uint4*)&Al[s][row][q * 8] = ra[s * 4 + h];
            }
    };
    auto loadB = [&](int kt) {
        #pragma unroll
        for (int s = 0; s < NS; ++s)
            #pragma unroll
            for (int h = 0; h < 4; ++h) {
                int c = tid + h * 256, row = c >> 3, q = c & 7;
                int gn = n0 + row;
                uint4 v = {0u, 0u, 0u, 0u};
                if (gn < p.N) v = *(const uint4*)(Bpu + (ll)s * p.sBp + (size_t)gn * p.ldb + kt * BK + q * 8);
                rb[s * 4 + h] = v;
            }
    };
    auto storeB = [&]() {
        #pragma unroll
        for (int s = 0; s < NS; ++s)
            #pragma unroll
            for (int h = 0; h < 4; ++h) {
                int c = tid + h * 256, row = c >> 3, q = c & 7;
                *(uint4*)&Bl[s][row][q * 8] = rb[s * 4 + h];
            }
    };
    // BTRANS=0: f32 [K][N] B stream, named register sets for depth-2 pipeline
    auto loadBf = [&](float (&dst)[32], int kt) {
        int gn = n0 + (tid & 127);
        int kb = (tid >> 7) * 32;
        #pragma unroll
        for (int i = 0; i < 32; ++i) {
            float v = 0.f;
            if (gn < p.N) v = Bpf[(size_t)(k0 + kt * BK + kb + i) * p.ldb + gn];
            dst[i] = v;
        }
    };
    auto storeBf = [&](const float (&src)[32]) {
        int col = tid & 127;
        int kb = (tid >> 7) * 32;
        #pragma unroll
        for (int i = 0; i < 8; ++i) {
            u16 t0[4], t1[4];
            #pragma unroll
            for (int e = 0; e < 4; ++e) split2h(src[i * 4 + e], t0[e], t1[e]);
            *(uint2*)&Bl[0][col][kb + i * 4] = *(uint2*)t0;
            if (NS == 2) *(uint2*)&Bl[1][col][kb + i * 4] = *(uint2*)t1;
        }
    };
    auto mfmaPhase = [&]() {
        #pragma unroll
        for (int kt2 = 0; kt2 < 2; ++kt2) {
            f16x8 b0r[4], b1r[4];
            #pragma unroll
            for (int j = 0; j < 4; ++j) {
                b0r[j] = *(const f16x8*)&Bl[0][wn + j * 16 + ar][kt2 * 32 + kg];
                if (NS == 2) b1r[j] = *(const f16x8*)&Bl[1][wn + j * 16 + ar][kt2 * 32 + kg];
            }
            #pragma unroll
            for (int i = 0; i < 4; ++i) {
                f16x8 a0 = *(const f16x8*)&Al[0][wm + i * 16 + ar][kt2 * 32 + kg];
                f16x8 a1;
                if (NS == 2) a1 = *(const f16x8*)&Al[1][wm + i * 16 + ar][kt2 * 32 + kg];
                #pragma unroll
                for (int j = 0; j < 4; ++j) {
                    acc0[i][j] = MFMA16(a0, b0r[j], acc0[i][j]);
                    if (NS == 2) {
                        acc1[i][j] = MFMA16(a0, b1r[j], acc1[i][j]);
                        acc1[i][j] = MFMA16(a1, b0r[j], acc1[i][j]);
                    }
                }
            }
        }
    };

    if (BTRANS) {
        loadA(0); loadB(0);
        for (int kt = 0; kt < nkt; ++kt) {
            storeA(); storeB();
            __syncthreads();
            if (kt + 1 < nkt) { loadA(kt + 1); loadB(kt + 1); }   // fly under 2x MFMA phase
            mfmaPhase();
            __syncthreads();
        }
    } else {
        // depth-2 pipeline on the slow f32 weight stream (w1/w2): loads lead by 2 k-iters,
        // storeBf waits only on its own set (counted vmcnt), the other set stays in flight.
        float rbf_e[32], rbf_o[32];
        loadA(0);
        loadBf(rbf_e, 0);
        if (nkt > 1) loadBf(rbf_o, 1);
        int kt = 0;
        while (true) {
            // even sub-iter
            storeA(); storeBf(rbf_e);
            __syncthreads();
            if (kt + 1 < nkt) loadA(kt + 1);
            if (kt + 2 < nkt) loadBf(rbf_e, kt + 2);
            mfmaPhase();
            __syncthreads();
            ++kt; if (kt >= nkt) break;
            // odd sub-iter
            storeA(); storeBf(rbf_o);
            __syncthreads();
            if (kt + 1 < nkt) loadA(kt + 1);
            if (kt + 2 < nkt) loadBf(rbf_o, kt + 2);
            mfmaPhase();
            __syncthreads();
            ++kt; if (kt >= nkt) break;
        }
    }

    const bool doPart = (p.flags & 16);
    float* Cpart = doPart ? ((float*)p.C + (ll)slice * p.partStride + zC) : nullptr;
    const float* biasp = (p.flags & 1) ? (p.bias + (ll)z * p.biasStride) : nullptr;
    u16* C0 = (!doPart && (p.flags & 8)) ? ((u16*)p.C + zC) : nullptr;
    u16* C1 = C0 ? (C0 + p.sCp) : nullptr;
    float* Cf = (!doPart && !(p.flags & 8)) ? ((float*)p.C + zC) : nullptr;
    #pragma unroll
    for (int i = 0; i < 4; ++i) {
        #pragma unroll
        for (int j = 0; j < 4; ++j) {
            int gc = n0 + wn + j * 16 + (lane & 15);
            if (gc >= p.N) continue;
            int gr0 = m0 + wm + i * 16 + (lane >> 4) * 4;
            #pragma unroll
            for (int r = 0; r < 4; ++r) {
                int gr = gr0 + r;
                if (gr >= p.M) continue;
                float v = acc0[i][j][r];
                if (NS == 2) v += acc1[i][j][r] * (1.0f / 4096.0f);
                v *= p.alpha;
                size_t off = (size_t)gr * p.ldc + gc;
                if (doPart) { Cpart[off] = v; continue; }
                if (p.flags & 1) v = __fadd_rn(v, biasp[gc]);
                if (p.flags & 2) v = fmaxf(v, 0.f);
                if (p.flags & 8) { u16 h0, h1; split2h(v, h0, h1); C0[off] = h0; C1[off] = h1; }
                else Cf[off] = v;
            }
        }
    }
}

// ---------------- fused flash attention (T5: setprio around MFMA clusters) ----------------
__global__ __launch_bounds__(256) void flash_kernel(
    const u16* __restrict__ qkvp, ll sQp,
    const u16* __restrict__ vTp, ll sVp,
    const unsigned char* __restrict__ pad,
    u16* __restrict__ attnp, ll sOp) {
    __shared__ u16 KV[2][64][72];
    __shared__ u16 Pl[2][4][16][72];

    int L = blockIdx.x;                 // 384 blocks, 384%8==0
    int c = (L & 7) * 48 + (L >> 3);
    int bh = c >> 3, qt = c & 7;
    int b = bh / HH, h = bh % HH;
    int lane = threadIdx.x & 63, wv = threadIdx.x >> 6;
    int qbase = b * SS + qt * 64 + wv * 16;

    int spl = threadIdx.x >> 7;
    int srr = threadIdx.x & 127;
    int srow = srr >> 1, shalf = srr & 1;

    f16x8 qf[2][2];
    {
        const u16* qr = qkvp + (size_t)(qbase + (lane & 15)) * (3 * DD) + h * HD + (lane >> 4) * 8;
        #pragma unroll
        for (int kt2 = 0; kt2 < 2; ++kt2)
            #pragma unroll
            for (int pl = 0; pl < 2; ++pl)
                qf[kt2][pl] = *(const f16x8*)(qr + (ll)pl * sQp + kt2 * 32);
    }

    f32x4 S[32];
    #pragma unroll
    for (int kv = 0; kv < 8; ++kv) {
        const u16* gk = qkvp + (size_t)(b * SS + kv * 64 + srow) * (3 * DD) + DD + h * HD + (ll)spl * sQp;
        #pragma unroll
        for (int qq = 0; qq < 4; ++qq) {
            int off = shalf * 32 + qq * 8;
            *(uint4*)&KV[spl][srow][off] = *(const uint4*)(gk + off);
        }
        __syncthreads();
        __builtin_amdgcn_s_setprio(1);
        #pragma unroll
        for (int nf = 0; nf < 4; ++nf) {
            f32x4 a0 = {}, a1 = {};
            #pragma unroll
            for (int kt2 = 0; kt2 < 2; ++kt2) {
                f16x8 b0 = *(const f16x8*)&KV[0][nf * 16 + (lane & 15)][kt2 * 32 + (lane >> 4) * 8];
                f16x8 b1 = *(const f16x8*)&KV[1][nf * 16 + (lane & 15)][kt2 * 32 + (lane >> 4) * 8];
                a0 = MFMA16(qf[kt2][0], b0, a0);
                a1 = MFMA16(qf[kt2][0], b1, a1);
                a1 = MFMA16(qf[kt2][1], b0, a1);
            }
            int col = kv * 64 + nf * 16 + (lane & 15);
            bool msk = pad[b * SS + col] != 0;
            #pragma unroll
            for (int r = 0; r < 4; ++r) {
                float v = (a0[r] + a1[r] * (1.0f / 4096.0f)) * 0.125f;
                S[kv * 4 + nf][r] = msk ? -1e9f : v;
            }
        }
        __builtin_amdgcn_s_setprio(0);
        __syncthreads();
    }

    float mx[4] = {-1e30f, -1e30f, -1e30f, -1e30f}, sm[4] = {0.f, 0.f, 0.f, 0.f}, inv[4];
    #pragma unroll
    for (int f = 0; f < 32; ++f)
        #pragma unroll
        for (int r = 0; r < 4; ++r) mx[r] = fmaxf(mx[r], S[f][r]);
    #pragma unroll
    for (int r = 0; r < 4; ++r) {
        #pragma unroll
        for (int off = 1; off < 16; off <<= 1) mx[r] = fmaxf(mx[r], __shfl_xor(mx[r], off));
    }
    #pragma unroll
    for (int f = 0; f < 32; ++f)
        #pragma unroll
        for (int r = 0; r < 4; ++r) { float e = expf(S[f][r] - mx[r]); S[f][r] = e; sm[r] += e; }
    #pragma unroll
    for (int r = 0; r < 4; ++r) {
        #pragma unroll
        for (int off = 1; off < 16; off <<= 1) sm[r] += __shfl_xor(sm[r], off);
        inv[r] = 1.f / sm[r];
    }

    f32x4 p0[4] = {}, p1[4] = {};
    #pragma unroll
    for (int kv = 0; kv < 8; ++kv) {
        const u16* gv = vTp + (size_t)bh * HD * SS + (size_t)srow * SS + kv * 64 + (ll)spl * sVp;
        #pragma unroll
        for (int qq = 0; qq < 4; ++qq) {
            int off = shalf * 32 + qq * 8;
            *(uint4*)&KV[spl][srow][off] = *(const uint4*)(gv + off);
        }
        #pragma unroll
        for (int nf = 0; nf < 4; ++nf)
            #pragma unroll
            for (int r = 0; r < 4; ++r) {
                float v = S[kv * 4 + nf][r] * inv[r];
                u16 h0, h1; split2h(v, h0, h1);
                Pl[0][wv][(lane >> 4) * 4 + r][nf * 16 + (lane & 15)] = h0;
                Pl[1][wv][(lane >> 4) * 4 + r][nf * 16 + (lane & 15)] = h1;
            }
        __syncthreads();
        f16x8 pa[2][2];
        #pragma unroll
        for (int kt2 = 0; kt2 < 2; ++kt2)
            #pragma unroll
            for (int pl = 0; pl < 2; ++pl)
                pa[kt2][pl] = *(const f16x8*)&Pl[pl][wv][lane & 15][kt2 * 32 + (lane >> 4) * 8];
        __builtin_amdgcn_s_setprio(1);
        #pragma unroll
        for (int df = 0; df < 4; ++df) {
            #pragma unroll
            for (int kt2 = 0; kt2 < 2; ++kt2) {
                f16x8 v0 = *(const f16x8*)&KV[0][df * 16 + (lane & 15)][kt2 * 32 + (lane >> 4) * 8];
                f16x8 v1 = *(const f16x8*)&KV[1][df * 16 + (lane & 15)][kt2 * 32 + (lane >> 4) * 8];
                p0[df] = MFMA16(pa[kt2][0], v0, p0[df]);
                p1[df] = MFMA16(pa[kt2][0], v1, p1[df]);
                p1[df] = MFMA16(pa[kt2][1], v0, p1[df]);
            }
        }
        __builtin_amdgcn_s_setprio(0);
        __syncthreads();
    }

    #pragma unroll
    for (int df = 0; df < 4; ++df)
        #pragma unroll
        for (int r = 0; r < 4; ++r) {
            float v = p0[df][r] + p1[df][r] * (1.0f / 4096.0f);
            int row = qbase + (lane >> 4) * 4 + r;
            int col = h * HD + df * 16 + (lane & 15);
            u16 h0, h1; split2h(v, h0, h1);
            attnp[(size_t)row * DD + col] = h0;
            attnp[(size_t)row * DD + col + sOp] = h1;
        }
}

// ---------------- split-K reduce ----------------
struct RedP {
    const float* part = nullptr; ll partStride = 0; int KS = 1;
    float* outf = nullptr;
    u16* o0 = nullptr; ll planeStride = 0;
    const float* bias = nullptr; ll biasStride = 0; ll batchElems = 1; int Nc = 1;
    const float* src = nullptr;
    ll total = 0; int mode = 0;   // 1=bias 2=relu 4=src 8=planes-out
};
__global__ void reduce_kernel(RedP p) {
    ll e0 = ((ll)blockIdx.x * 256 + threadIdx.x) * 4;
    if (e0 >= p.total) return;
    float4 s = *(const float4*)(p.part + e0);
    for (int k = 1; k < p.KS; ++k) {
        float4 t = *(const float4*)(p.part + (ll)k * p.partStride + e0);
        s.x += t.x; s.y += t.y; s.z += t.z; s.w += t.w;
    }
    if (p.mode & 1) {
        ll b = e0 / p.batchElems;
        int d = (int)(e0 % p.Nc);
        float4 bv = *(const float4*)(p.bias + b * p.biasStride + d);
        s.x = __fadd_rn(s.x, bv.x); s.y = __fadd_rn(s.y, bv.y);
        s.z = __fadd_rn(s.z, bv.z); s.w = __fadd_rn(s.w, bv.w);
    }
    if (p.mode & 4) {
        float4 t = *(const float4*)(p.src + e0);
        s.x = __fadd_rn(s.x, t.x); s.y = __fadd_rn(s.y, t.y);
        s.z = __fadd_rn(s.z, t.z); s.w = __fadd_rn(s.w, t.w);
    }
    if (p.mode & 2) { s.x = fmaxf(s.x, 0.f); s.y = fmaxf(s.y, 0.f); s.z = fmaxf(s.z, 0.f); s.w = fmaxf(s.w, 0.f); }
    if (p.mode & 8) {
        u16 t0[4], t1[4];
        float vv[4] = {s.x, s.y, s.z, s.w};
        #pragma unroll
        for (int e = 0; e < 4; ++e) split2h(vv[e], t0[e], t1[e]);
        *(uint2*)(p.o0 + e0) = *(uint2*)t0;
        *(uint2*)(p.o0 + p.planeStride + e0) = *(uint2*)t1;
    } else {
        *(float4*)(p.outf + e0) = s;
    }
}

// ---------------- weight split prepass ----------------
__global__ void wsplit_kernel(const float* __restrict__ w, u16* __restrict__ p0,
                              ll planeStride, ll total) {
    ll e0 = ((ll)blockIdx.x * 256 + threadIdx.x) * 4;
    if (e0 >= total) return;
    float4 v = *(const float4*)(w + e0);
    u16 t0[4], t1[4];
    float vv[4] = {v.x, v.y, v.z, v.w};
    #pragma unroll
    for (int e = 0; e < 4; ++e) split2h(vv[e], t0[e], t1[e]);
    *(uint2*)(p0 + e0) = *(uint2*)t0;
    *(uint2*)(p0 + planeStride + e0) = *(uint2*)t1;
}

// ---------------- V transpose ----------------
__global__ void vtrans_kernel(const u16* __restrict__ qkvp, ll sQp,
                              u16* __restrict__ vTp, ll sVp) {
    __shared__ float t[32][33];
    int z = blockIdx.z;
    int b = z / HH, h = z % HH;
    int c0 = blockIdx.x * 32, r0 = blockIdx.y * 32;
    int tx = threadIdx.x, ty = threadIdx.y;
    const u16* in = qkvp + (size_t)(b * SS) * (3 * DD) + 2 * DD + h * HD;
    #pragma unroll
    for (int i = 0; i < 32; i += 8) {
        size_t o = (size_t)(r0 + ty + i) * (3 * DD) + c0 + tx;
        t[ty + i][tx] = rec2h(in[o], in[o + sQp]);
    }
    __syncthreads();
    u16* out = vTp + (size_t)z * HD * SS;
    #pragma unroll
    for (int i = 0; i < 32; i += 8) {
        size_t o = (size_t)(c0 + ty + i) * SS + r0 + tx;
        u16 h0, h1; split2h(t[tx][ty + i], h0, h1);
        out[o] = h0; out[o + sVp] = h1;
    }
}

// ---------------- pe table (numpy f32 chain) ----------------
__global__ void pe_kernel(float* __restrict__ pe) {
    int s = blockIdx.x, tid = threadIdx.x;
    const float lg = 9.210340371976184f;
    #pragma unroll
    for (int j = 0; j < 3; ++j) {
        int d = j * 256 + tid;
        int half = d >> 1;
        float fi = (float)(2 * half) / 768.0f;
        float arg = __fmul_rn(-fi, lg);
        float freq = (float)exp((double)arg);
        float ang = __fmul_rn((float)s, freq);
        double da = (double)ang;
        pe[(size_t)s * DD + d] = (d & 1) ? (float)cos(da) : (float)sin(da);
    }
}

__global__ void embed_kernel(const int* __restrict__ src, const float* __restrict__ emb,
                             const float* __restrict__ pe, float* __restrict__ x) {
    int t = blockIdx.x, tid = threadIdx.x;
    int s = t & (SS - 1);
    int tok = src[t];
    const float sq = 27.712812921102035f;
    #pragma unroll
    for (int j = 0; j < 3; ++j) {
        int d = j * 256 + tid;
        float e = emb[(size_t)tok * DD + d];
        x[(size_t)t * DD + d] = __fadd_rn(__fmul_rn(e, sq), pe[(size_t)s * DD + d]);
    }
}

// ---------------- layernorm (op nullable) ----------------
__global__ void ln_kernel(const float* __restrict__ x, const float* __restrict__ g,
                          const float* __restrict__ b, float* __restrict__ outf,
                          u16* __restrict__ op, ll planeStride) {
    int t = blockIdx.x, tid = threadIdx.x;
    const float* xr = x + (size_t)t * DD;
    float v[3], s = 0.f, sq = 0.f;
    #pragma unroll
    for (int j = 0; j < 3; ++j) { v[j] = xr[tid + j * 256]; s += v[j]; sq += v[j] * v[j]; }
    #pragma unroll
    for (int off = 32; off; off >>= 1) { s += __shfl_xor(s, off); sq += __shfl_xor(sq, off); }
    __shared__ float rs[4], rq[4];
    int wid = tid >> 6;
    if ((tid & 63) == 0) { rs[wid] = s; rq[wid] = sq; }
    __syncthreads();
    s = rs[0] + rs[1] + rs[2] + rs[3];
    sq = rq[0] + rq[1] + rq[2] + rq[3];
    float mu = s / 768.0f;
    float var = sq / 768.0f - mu * mu;
    float rstd = rsqrtf(var + 1e-5f);
    #pragma unroll
    for (int j = 0; j < 3; ++j) {
        int d = tid + j * 256;
        float y = __fadd_rn(__fmul_rn(__fmul_rn(v[j] - mu, rstd), g[d]), b[d]);
        if (outf) outf[(size_t)t * DD + d] = y;
        if (op) {
            size_t o = (size_t)t * DD + d;
            u16 h0, h1; split2h(y, h0, h1);
            op[o] = h0; op[o + planeStride] = h1;
        }
    }
}

// ---------------- fused LN2 + router ----------------
__global__ void ln2_router_kernel(const float* __restrict__ x, const float* __restrict__ g,
                                  const float* __restrict__ b, const float* __restrict__ wr,
                                  const unsigned char* __restrict__ pad,
                                  u16* __restrict__ op, ll planeStride,
                                  float* __restrict__ probs, float* __restrict__ lsev,
                                  float* __restrict__ gate, int* __restrict__ idx) {
    int t = blockIdx.x, tid = threadIdx.x;
    const float* xr = x + (size_t)t * DD;
    float v[3], s = 0.f, sq = 0.f;
    #pragma unroll
    for (int j = 0; j < 3; ++j) { v[j] = xr[tid + j * 256]; s += v[j]; sq += v[j] * v[j]; }
    #pragma unroll
    for (int off = 32; off; off >>= 1) { s += __shfl_xor(s, off); sq += __shfl_xor(sq, off); }
    __shared__ float rs[4], rq[4];
    __shared__ float ra[4][8];
    int wid = tid >> 6;
    if ((tid & 63) == 0) { rs[wid] = s; rq[wid] = sq; }
    __syncthreads();
    s = rs[0] + rs[1] + rs[2] + rs[3];
    sq = rq[0] + rq[1] + rq[2] + rq[3];
    float mu = s / 768.0f;
    float var = sq / 768.0f - mu * mu;
    float rstd = rsqrtf(var + 1e-5f);
    float a[8] = {0.f, 0.f, 0.f, 0.f, 0.f, 0.f, 0.f, 0.f};
    #pragma unroll
    for (int j = 0; j < 3; ++j) {
        int d = tid + j * 256;
        float y = __fadd_rn(__fmul_rn(__fmul_rn(v[j] - mu, rstd), g[d]), b[d]);
        size_t o = (size_t)t * DD + d;
        u16 h0, h1; split2h(y, h0, h1);
        op[o] = h0; op[o + planeStride] = h1;
        const float* w = wr + (size_t)d * EE;
        #pragma unroll
        for (int e = 0; e < 8; ++e) a[e] += y * w[e];
    }
    #pragma unroll
    for (int off = 32; off; off >>= 1)
        #pragma unroll
        for (int e = 0; e < 8; ++e) a[e] += __shfl_xor(a[e], off);
    if ((tid & 63) == 0)
        #pragma unroll
        for (int e = 0; e < 8; ++e) ra[wid][e] = a[e];
    __syncthreads();
    if (tid == 0) {
        #pragma unroll
        for (int e = 0; e < 8; ++e) a[e] = ra[0][e] + ra[1][e] + ra[2][e] + ra[3][e];
        int vm = (pad[t] == 0);
        float mx = a[0]; int bi = 0;
        #pragma unroll
        for (int e = 1; e < 8; ++e) if (a[e] > mx) { mx = a[e]; bi = e; }
        float ex[8], sum = 0.f;
        #pragma unroll
        for (int e = 0; e < 8; ++e) { ex[e] = expf(a[e] - mx); sum += ex[e]; }
        float inv = 1.f / sum;
        #pragma unroll
        for (int e = 0; e < 8; ++e) probs[(size_t)t * EE + e] = vm ? ex[e] * inv : 0.f;
        lsev[t] = vm ? (mx + logf(sum)) : 0.f;
        gate[t] = ex[bi] * inv;
        idx[t] = vm ? bi : -1;
    }
}

// ---------------- routing scan ----------------
__global__ void route_scan_kernel(const int* __restrict__ idx, const float* __restrict__ probs,
                                  const float* __restrict__ lsev, int* __restrict__ slot,
                                  int* __restrict__ tos, float* __restrict__ acc) {
    int lane = threadIdx.x;
    int base = lane * 32;
    int ev[32];
    int c[8] = {0, 0, 0, 0, 0, 0, 0, 0};
    #pragma unroll
    for (int i = 0; i < 32; ++i) {
        int e = idx[base + i];
        ev[i] = e;
        #pragma unroll
        for (int q = 0; q < 8; ++q) c[q] += (e == q);
    }
    int excl[8], tot[8];
    #pragma unroll
    for (int e = 0; e < 8; ++e) {
        int v = c[e];
        #pragma unroll
        for (int off = 1; off < 64; off <<= 1) {
            int n = __shfl_up(v, off);
            if (lane >= off) v += n;
        }
        excl[e] = v - c[e];
        tot[e] = __shfl(v, 63);
    }
    int r[8];
    #pragma unroll
    for (int e = 0; e < 8; ++e) r[e] = excl[e];
    #pragma unroll
    for (int i = 0; i < 32; ++i) {
        int t = base + i, e = ev[i], s = -1;
        if (e >= 0) {
            int pos = 0;
            #pragma unroll
            for (int q = 0; q < 8; ++q) if (e == q) { r[q]++; pos = r[q]; }
            if (pos <= CAP) { s = e * CAP + pos - 1; tos[s] = t; }
        }
        slot[t] = s;
    }
    float pa[8] = {0.f, 0.f, 0.f, 0.f, 0.f, 0.f, 0.f, 0.f};
    float l2 = 0.f, vld = 0.f;
    #pragma unroll
    for (int i = 0; i < 32; ++i) {
        int t = base + i;
        float lv = lsev[t];
        l2 += lv * lv;
        if (ev[i] >= 0) vld += 1.f;
        #pragma unroll
        for (int e = 0; e < 8; ++e) pa[e] += probs[(size_t)t * EE + e];
    }
    #pragma unroll
    for (int off = 32; off; off >>= 1) {
        #pragma unroll
        for (int e = 0; e < 8; ++e) pa[e] += __shfl_xor(pa[e], off);
        l2 += __shfl_xor(l2, off);
        vld += __shfl_xor(vld, off);
    }
    if (lane == 0) {
        float denom = fmaxf(vld, 1.f);
        float lb = 0.f;
        #pragma unroll
        for (int e = 0; e < 8; ++e) lb += (pa[e] / denom) * ((float)tot[e] / denom);
        lb *= 8.f;
        acc[0] += lb;
        acc[1] += l2 / denom;
    }
}

// ---------------- gather ----------------
__global__ void gather_kernel(const int* __restrict__ tos, const u16* __restrict__ xnp,
                              ll sXp, u16* __restrict__ einp, ll sEp) {
    int s = blockIdx.x;
    int tid = threadIdx.x;
    if (tid >= 192) return;
    int pl = tid / 96, q = tid % 96;
    int t = tos[s];
    uint4 v = {0u, 0u, 0u, 0u};
    if (t >= 0) v = *(const uint4*)(xnp + (ll)pl * sXp + (size_t)t * DD + q * 8);
    *(uint4*)(einp + (ll)pl * sEp + (size_t)s * DD + q * 8) = v;
}

// ---------------- fused FFN2-reduce + combine ----------------
__global__ void combine2_kernel(const int* __restrict__ slot, const float* __restrict__ gate,
                                const float* __restrict__ part, ll partStride, int KS,
                                const float* __restrict__ b2, float* __restrict__ x) {
    int t = blockIdx.x, tid = threadIdx.x;
    int s = slot[t];
    if (s < 0) return;
    float gv = gate[t];
    int e = s / CAP;
    #pragma unroll
    for (int j = 0; j < 3; ++j) {
        int d = j * 256 + tid;
        size_t o = (size_t)s * DD + d;
        float v = part[o];
        for (int k = 1; k < KS; ++k) v += part[(ll)k * partStride + o];
        v = __fadd_rn(v, b2[(size_t)e * DD + d]);
        size_t ox = (size_t)t * DD + d;
        x[ox] = __fadd_rn(x[ox], __fmul_rn(gv, v));
    }
}

__global__ void finalize_kernel(const float* __restrict__ acc, float* __restrict__ out) {
    out[(size_t)TT * DD] = acc[0] * (1.f / NLAYER);
    out[(size_t)TT * DD + 1] = acc[1] * (1.f / NLAYER);
}

// ---------------- host ----------------
static inline void run_gemm(bool btrans, int ns, const GemmP& p, dim3 grid, hipStream_t s) {
    if (btrans) {
        if (ns == 2) gemm_kernel<true, 2><<<grid, 256, 0, s>>>(p);
        else gemm_kernel<true, 1><<<grid, 256, 0, s>>>(p);
    } else {
        if (ns == 2) gemm_kernel<false, 2><<<grid, 256, 0, s>>>(p);
        else gemm_kernel<false, 1><<<grid, 256, 0, s>>>(p);
    }
}
static inline void run_reduce(const RedP& r, hipStream_t s) {
    reduce_kernel<<<(int)((r.total / 4 + 255) / 256), 256, 0, s>>>(r);
}

extern "C" void kernel_launch(void* const* d_in, const int* in_sizes, int n_in,
                              void* d_out, int out_size, void* d_ws, size_t ws_size,
                              hipStream_t stream) {
    const int* src = (const int*)d_in[0];
    const unsigned char* pad = (const unsigned char*)d_in[1];
    const float* emb = (const float*)d_in[2];
    const float* qkv_w = (const float*)d_in[3];
    const float* qkv_b = (const float*)d_in[4];
    const float* out_w = (const float*)d_in[5];
    const float* out_b = (const float*)d_in[6];
    const float* wr = (const float*)d_in[7];
    const float* w1 = (const float*)d_in[8];
    const float* b1 = (const float*)d_in[9];
    const float* w2 = (const float*)d_in[10];
    const float* b2 = (const float*)d_in[11];
    const float* ln1_g = (const float*)d_in[12];
    const float* ln1_b = (const float*)d_in[13];
    const float* ln2_g = (const float*)d_in[14];
    const float* ln2_b = (const float*)d_in[15];
    const float* lnf_g = (const float*)d_in[16];
    const float* lnf_b = (const float*)d_in[17];

    char* w = (char*)d_ws;
    size_t off = 0;
    auto alloc = [&](size_t bytes) -> void* {
        void* p = w + off;
        off += (bytes + 255) & ~(size_t)255;
        return p;
    };
    float* x      = (float*)alloc((size_t)TT * DD * 4);
    float* peT    = (float*)alloc((size_t)SS * DD * 4);
    u16*   xnp    = (u16*)  alloc((size_t)2 * TT * DD * 2);
    u16*   qkvp   = (u16*)  alloc((size_t)2 * TT * 3 * DD * 2);
    u16*   vTp    = (u16*)  alloc((size_t)2 * BB * HH * HD * SS * 2);
    u16*   attnp  = (u16*)  alloc((size_t)2 * TT * DD * 2);
    u16*   einp   = (u16*)  alloc((size_t)2 * EE * CAP * DD * 2);
    u16*   hidp   = (u16*)  alloc((size_t)2 * EE * CAP * DFF * 2);
    char*  regB   = (char*) alloc((size_t)2 * TT * 3 * DD * 4);      // partials (max: qkv KS2)
    u16*   qkvwp  = (u16*)  alloc((size_t)2 * NLAYER * 3 * DD * DD * 2);
    u16*   owp    = (u16*)  alloc((size_t)2 * NLAYER * DD * DD * 2);
    float* probs  = (float*)alloc((size_t)TT * EE * 4);
    float* lsev   = (float*)alloc((size_t)TT * 4);
    float* gate   = (float*)alloc((size_t)TT * 4);
    int*   idx    = (int*)  alloc((size_t)TT * 4);
    int*   slot   = (int*)  alloc((size_t)TT * 4);
    int*   tos    = (int*)  alloc((size_t)EE * CAP * 4);
    float* accb   = (float*)alloc(256);
    if (off > ws_size) return;

    float* qkvpart = (float*)regB;   // KS2 x TT*3DD = 37.7MB
    float* oppart  = (float*)regB;   // KS4 x TT*DD  = 25.2MB
    float* ffnpart = (float*)regB;   // KS4 x E*CAP*DD = 31.5MB

    hipMemsetAsync(accb, 0, 8, stream);
    pe_kernel<<<SS, 256, 0, stream>>>(peT);
    embed_kernel<<<TT, 256, 0, stream>>>(src, emb, peT, x);

    {
        ll tq = (ll)NLAYER * 3 * DD * DD;
        wsplit_kernel<<<(int)((tq / 4 + 255) / 256), 256, 0, stream>>>(qkv_w, qkvwp, tq, tq);
        ll to = (ll)NLAYER * DD * DD;
        wsplit_kernel<<<(int)((to / 4 + 255) / 256), 256, 0, stream>>>(out_w, owp, to, to);
    }

    for (int l = 0; l < NLAYER; ++l) {
        const int nsF = (l < NLAYER - 1) ? 2 : 1;
        ln_kernel<<<TT, 256, 0, stream>>>(x, ln1_g + l * DD, ln1_b + l * DD, nullptr, xnp, (ll)TT * DD);

        // QKV (KS=2): kslice 384 = 6 k-iters
        {
            GemmP p;
            p.A = xnp; p.sAp = (ll)TT * DD; p.lda = DD;
            p.B = qkvwp + (size_t)l * 3 * DD * DD; p.sBp = (ll)NLAYER * 3 * DD * DD; p.ldb = DD;
            p.C = qkvpart; p.ldc = 3 * DD;
            p.M = TT; p.N = 3 * DD; p.K = DD;
            p.flags = 16; p.KS = 2; p.partStride = (ll)TT * 3 * DD;
            p.Jc = 4;
            run_gemm(true, 2, p, dim3(18, 16, 2), stream);
        }
        {
            RedP r;
            r.part = qkvpart; r.partStride = (ll)TT * 3 * DD; r.KS = 2;
            r.o0 = qkvp; r.planeStride = (ll)TT * 3 * DD;
            r.bias = qkv_b + (size_t)l * 3 * DD; r.biasStride = 0; r.batchElems = (ll)TT * 3 * DD; r.Nc = 3 * DD;
            r.total = (ll)TT * 3 * DD; r.mode = 1 | 8;
            run_reduce(r, stream);
        }
        vtrans_kernel<<<dim3(HD / 32, SS / 32, BB * HH), dim3(32, 8), 0, stream>>>(
            qkvp, (ll)TT * 3 * DD, vTp, (ll)BB * HH * HD * SS);
        flash_kernel<<<BB * HH * 8, 256, 0, stream>>>(
            qkvp, (ll)TT * 3 * DD, vTp, (ll)BB * HH * HD * SS, pad, attnp, (ll)TT * DD);
        // out-proj (KS=4): kslice 192 = 3 k-iters; reduce adds bias + residual
        {
            GemmP p;
            p.A = attnp; p.sAp = (ll)TT * DD; p.lda = DD;
            p.B = owp + (size_t)l * DD * DD; p.sBp = (ll)NLAYER * DD * DD; p.ldb = DD;
            p.C = oppart; p.ldc = DD;
            p.M = TT; p.N = DD; p.K = DD;
            p.flags = 16; p.KS = 4; p.partStride = (ll)TT * DD;
            p.Jc = 8;
            run_gemm(true, 2, p, dim3(6, 16, 4), stream);
        }
        {
            RedP r;
            r.part = oppart; r.partStride = (ll)TT * DD; r.KS = 4;
            r.outf = x;
            r.bias = out_b + (size_t)l * DD; r.biasStride = 0; r.batchElems = (ll)TT * DD; r.Nc = DD;
            r.src = x;
            r.total = (ll)TT * DD; r.mode = 1 | 4;
            run_reduce(r, stream);
        }
        // fused LN2 + router
        ln2_router_kernel<<<TT, 256, 0, stream>>>(x, ln2_g + l * DD, ln2_b + l * DD,
                                                  wr + (size_t)l * DD * EE, pad,
                                                  xnp, (ll)TT * DD, probs, lsev, gate, idx);
        hipMemsetAsync(tos, 0xFF, (size_t)EE * CAP * 4, stream);
        route_scan_kernel<<<1, 64, 0, stream>>>(idx, probs, lsev, slot, tos, accb);
        gather_kernel<<<EE * CAP, 256, 0, stream>>>(tos, xnp, (ll)TT * DD, einp, (ll)EE * CAP * DD);
        // FFN1 (KS=1, direct planes-out with bias+relu): 12 k-iters, 576 blocks
        {
            GemmP p;
            p.A = einp; p.sAp = (ll)EE * CAP * DD; p.lda = DD;
            p.modA = EE; p.sA1 = (ll)CAP * DD;
            p.B = w1 + (size_t)l * EE * DD * DFF; p.ldb = DFF;
            p.modB = EE; p.sB1 = (ll)DD * DFF;
            p.bias = b1 + (size_t)l * EE * DFF; p.biasStride = DFF;
            p.C = hidp; p.sCp = (ll)EE * CAP * DFF; p.ldc = DFF;
            p.modC = EE; p.sC1 = (ll)CAP * DFF;
            p.M = CAP; p.N = DFF; p.K = DD;
            p.flags = 1 | 2 | 8;
            p.Jc = 3;
            run_gemm(false, nsF, p, dim3(24, 3, EE), stream);
        }
        // FFN2 (KS=4): kslice 768 = 12 k-iters; combine2 sums partials + b2 into x
        {
            GemmP p;
            p.A = hidp; p.sAp = (ll)EE * CAP * DFF; p.lda = DFF;
            p.modA = EE; p.sA1 = (ll)CAP * DFF;
            p.B = w2 + (size_t)l * EE * DFF * DD; p.ldb = DD;
            p.modB = EE; p.sB1 = (ll)DFF * DD;
            p.C = ffnpart; p.ldc = DD; p.modC = EE; p.sC1 = (ll)CAP * DD;
            p.M = CAP; p.N = DD; p.K = DFF;
            p.flags = 16; p.KS = 4; p.partStride = (ll)EE * CAP * DD;
            p.Jc = 12;
            run_gemm(false, nsF, p, dim3(6, 3, EE * 4), stream);
        }
        combine2_kernel<<<TT, 256, 0, stream>>>(slot, gate, ffnpart, (ll)EE * CAP * DD, 4,
                                                b2 + (size_t)l * EE * DD, x);
    }
    ln_kernel<<<TT, 256, 0, stream>>>(x, lnf_g, lnf_b, (float*)d_out, nullptr, 0);
    finalize_kernel<<<1, 1, 0, stream>>>(accb, (float*)d_out);
}

// Round 13
// 748.646 us; speedup vs baseline: 2.3801x; 2.3801x over previous
//
#include <hip/hip_runtime.h>

#define BB 4
#define SS 512
#define DD 768
#define HH 12
#define NLAYER 2
#define EE 8
#define DFF 3072
#define TT 2048
#define CAP 320
#define HD 64

typedef unsigned short u16;
typedef long long ll;
typedef _Float16 f16x8 __attribute__((ext_vector_type(8)));
typedef float f32x4 __attribute__((ext_vector_type(4)));

union F16U { _Float16 h; u16 u; };

// fp16 two-term split: v = h0 + h1*2^-12 + err, |err| <= ~2^-24*|v|.
__device__ __forceinline__ void split2h(float v, u16& h0, u16& h1) {
    F16U c0; c0.h = (_Float16)v;
    float r = (v - (float)c0.h) * 4096.0f;
    F16U c1; c1.h = (_Float16)r;
    h0 = c0.u; h1 = c1.u;
}
__device__ __forceinline__ float rec2h(u16 a, u16 b) {
    F16U c0, c1; c0.u = a; c1.u = b;
    return (float)c0.h + (float)c1.h * (1.0f / 4096.0f);
}

#define MFMA16(a, b, c) __builtin_amdgcn_mfma_f32_16x16x32_f16(a, b, c, 0, 0, 0)

// ---------------- GEMM (BK=64) ----------------
struct GemmP {
    const u16* A = nullptr; ll sAp = 0;
    const void* B = nullptr; ll sBp = 0;
    const float* bias = nullptr; ll biasStride = 0;
    void* C = nullptr; ll sCp = 0;
    int M = 0, N = 0, K = 0, lda = 0, ldb = 0, ldc = 0;
    int modA = 1; ll sA1 = 0, sA2 = 0;
    int modB = 1; ll sB1 = 0, sB2 = 0;
    int modC = 1; ll sC1 = 0, sC2 = 0;
    float alpha = 1.f;
    int flags = 0;    // 1=bias 2=relu 8=planes-out 16=partial-out(split-K)
    int KS = 1; ll partStride = 0;
    int Jc = 1;       // XCD supertile chunk (must divide gridDim.y*gridDim.z)
};

#define BK 64
#define PADK 72   // 144B rows: 16B-aligned (b128 ok)

template<bool BTRANS, int NS>
__global__ __launch_bounds__(256) void gemm_kernel(GemmP p) {
    __shared__ u16 Al[NS][128][PADK];
    __shared__ u16 Bl[NS][128][PADK];
    const int tid = threadIdx.x;

    // ---- XCD supertile remap ----
    int bx, by, bz;
    {
        int gx = gridDim.x, gy = gridDim.y;
        int NBt = gx * gy * gridDim.z;
        int L = blockIdx.x + gx * (blockIdx.y + gy * blockIdx.z);
        int q = NBt >> 3, r = NBt & 7;
        int xcd = L & 7, wi = L >> 3;
        int c = (xcd < r) ? xcd * (q + 1) + wi : r * (q + 1) + (xcd - r) * q + wi;
        int Jc = p.Jc;
        int gxJ = gx * Jc;
        int sj = c / gxJ;
        int t = c - sj * gxJ;
        bx = t / Jc;
        int j = sj * Jc + (t - (t / Jc) * Jc);
        by = j % gy; bz = j / gy;
    }
    const int n0 = bx * 128, m0 = by * 128;
    const int slice = bz % p.KS;
    const int z = bz / p.KS;
    const int kslice = p.K / p.KS;
    const int k0 = slice * kslice;
    const int nkt = kslice >> 6;

    const u16* Ap = p.A + (ll)(z % p.modA) * p.sA1 + (ll)(z / p.modA) * p.sA2 + k0;
    const ll zB = (ll)(z % p.modB) * p.sB1 + (ll)(z / p.modB) * p.sB2;
    const ll zC = (ll)(z % p.modC) * p.sC1 + (ll)(z / p.modC) * p.sC2;
    const u16* Bpu = BTRANS ? ((const u16*)p.B + zB + k0) : nullptr;
    const float* Bpf = BTRANS ? nullptr : ((const float*)p.B + zB);

    const int lane = tid & 63, wid = tid >> 6;
    const int wm = (wid >> 1) * 64, wn = (wid & 1) * 64;
    const int ar = lane & 15, kg = (lane >> 4) * 8;

    f32x4 acc0[4][4] = {};
    f32x4 acc1[4][4] = {};

    uint4 ra[4 * NS];
    uint4 rb[4 * NS];
    float rbf[32];

    auto loadA = [&](int kt) {
        #pragma unroll
        for (int s = 0; s < NS; ++s)
            #pragma unroll
            for (int h = 0; h < 4; ++h) {
                int c = tid + h * 256, row = c >> 3, q = c & 7;
                int gm = m0 + row;
                uint4 v = {0u, 0u, 0u, 0u};
                if (gm < p.M) v = *(const uint4*)(Ap + (ll)s * p.sAp + (size_t)gm * p.lda + kt * BK + q * 8);
                ra[s * 4 + h] = v;
            }
    };
    auto storeA = [&]() {
        #pragma unroll
        for (int s = 0; s < NS; ++s)
            #pragma unroll
            for (int h = 0; h < 4; ++h) {
                int c = tid + h * 256, row = c >> 3, q = c & 7;
                *(uint4*)&Al[s][row][q * 8] = ra[s * 4 + h];
            }
    };
    auto loadB = [&](int kt) {
        if (BTRANS) {
            #pragma unroll
            for (int s = 0; s < NS; ++s)
                #pragma unroll
                for (int h = 0; h < 4; ++h) {
                    int c = tid + h * 256, row = c >> 3, q = c & 7;
                    int gn = n0 + row;
                    uint4 v = {0u, 0u, 0u, 0u};
                    if (gn < p.N) v = *(const uint4*)(Bpu + (ll)s * p.sBp + (size_t)gn * p.ldb + kt * BK + q * 8);
                    rb[s * 4 + h] = v;
                }
        } else {
            // f32 [K][N]: thread owns one column, 32 k-strided dwords (coalesced per row)
            int gn = n0 + (tid & 127);
            int kb = (tid >> 7) * 32;
            #pragma unroll
            for (int i = 0; i < 32; ++i) {
                float v = 0.f;
                if (gn < p.N) v = Bpf[(size_t)(k0 + kt * BK + kb + i) * p.ldb + gn];
                rbf[i] = v;
            }
        }
    };
    auto storeB = [&]() {
        if (BTRANS) {
            #pragma unroll
            for (int s = 0; s < NS; ++s)
                #pragma unroll
                for (int h = 0; h < 4; ++h) {
                    int c = tid + h * 256, row = c >> 3, q = c & 7;
                    *(uint4*)&Bl[s][row][q * 8] = rb[s * 4 + h];
                }
        } else {
            int col = tid & 127;
            int kb = (tid >> 7) * 32;
            #pragma unroll
            for (int i = 0; i < 8; ++i) {
                u16 t0[4], t1[4];
                #pragma unroll
                for (int e = 0; e < 4; ++e) split2h(rbf[i * 4 + e], t0[e], t1[e]);
                *(uint2*)&Bl[0][col][kb + i * 4] = *(uint2*)t0;
                if (NS == 2) *(uint2*)&Bl[1][col][kb + i * 4] = *(uint2*)t1;
            }
        }
    };

    loadA(0); loadB(0);
    for (int kt = 0; kt < nkt; ++kt) {
        storeA(); storeB();
        __syncthreads();
        if (kt + 1 < nkt) { loadA(kt + 1); loadB(kt + 1); }   // fly under 2x MFMA phase
        #pragma unroll
        for (int kt2 = 0; kt2 < 2; ++kt2) {
            f16x8 b0r[4], b1r[4];
            #pragma unroll
            for (int j = 0; j < 4; ++j) {
                b0r[j] = *(const f16x8*)&Bl[0][wn + j * 16 + ar][kt2 * 32 + kg];
                if (NS == 2) b1r[j] = *(const f16x8*)&Bl[1][wn + j * 16 + ar][kt2 * 32 + kg];
            }
            #pragma unroll
            for (int i = 0; i < 4; ++i) {
                f16x8 a0 = *(const f16x8*)&Al[0][wm + i * 16 + ar][kt2 * 32 + kg];
                f16x8 a1;
                if (NS == 2) a1 = *(const f16x8*)&Al[1][wm + i * 16 + ar][kt2 * 32 + kg];
                #pragma unroll
                for (int j = 0; j < 4; ++j) {
                    acc0[i][j] = MFMA16(a0, b0r[j], acc0[i][j]);
                    if (NS == 2) {
                        acc1[i][j] = MFMA16(a0, b1r[j], acc1[i][j]);
                        acc1[i][j] = MFMA16(a1, b0r[j], acc1[i][j]);
                    }
                }
            }
        }
        __syncthreads();
    }

    const bool doPart = (p.flags & 16);
    float* Cpart = doPart ? ((float*)p.C + (ll)slice * p.partStride + zC) : nullptr;
    const float* biasp = (p.flags & 1) ? (p.bias + (ll)z * p.biasStride) : nullptr;
    u16* C0 = (!doPart && (p.flags & 8)) ? ((u16*)p.C + zC) : nullptr;
    u16* C1 = C0 ? (C0 + p.sCp) : nullptr;
    float* Cf = (!doPart && !(p.flags & 8)) ? ((float*)p.C + zC) : nullptr;
    #pragma unroll
    for (int i = 0; i < 4; ++i) {
        #pragma unroll
        for (int j = 0; j < 4; ++j) {
            int gc = n0 + wn + j * 16 + (lane & 15);
            if (gc >= p.N) continue;
            int gr0 = m0 + wm + i * 16 + (lane >> 4) * 4;
            #pragma unroll
            for (int r = 0; r < 4; ++r) {
                int gr = gr0 + r;
                if (gr >= p.M) continue;
                float v = acc0[i][j][r];
                if (NS == 2) v += acc1[i][j][r] * (1.0f / 4096.0f);
                v *= p.alpha;
                size_t off = (size_t)gr * p.ldc + gc;
                if (doPart) { Cpart[off] = v; continue; }
                if (p.flags & 1) v = __fadd_rn(v, biasp[gc]);
                if (p.flags & 2) v = fmaxf(v, 0.f);
                if (p.flags & 8) { u16 h0, h1; split2h(v, h0, h1); C0[off] = h0; C1[off] = h1; }
                else Cf[off] = v;
            }
        }
    }
}

// ---------------- fused flash attention (T5: setprio around MFMA clusters) ----------------
__global__ __launch_bounds__(256) void flash_kernel(
    const u16* __restrict__ qkvp, ll sQp,
    const u16* __restrict__ vTp, ll sVp,
    const unsigned char* __restrict__ pad,
    u16* __restrict__ attnp, ll sOp) {
    __shared__ u16 KV[2][64][72];
    __shared__ u16 Pl[2][4][16][72];

    int L = blockIdx.x;                 // 384 blocks, 384%8==0
    int c = (L & 7) * 48 + (L >> 3);
    int bh = c >> 3, qt = c & 7;
    int b = bh / HH, h = bh % HH;
    int lane = threadIdx.x & 63, wv = threadIdx.x >> 6;
    int qbase = b * SS + qt * 64 + wv * 16;

    int spl = threadIdx.x >> 7;
    int srr = threadIdx.x & 127;
    int srow = srr >> 1, shalf = srr & 1;

    f16x8 qf[2][2];
    {
        const u16* qr = qkvp + (size_t)(qbase + (lane & 15)) * (3 * DD) + h * HD + (lane >> 4) * 8;
        #pragma unroll
        for (int kt2 = 0; kt2 < 2; ++kt2)
            #pragma unroll
            for (int pl = 0; pl < 2; ++pl)
                qf[kt2][pl] = *(const f16x8*)(qr + (ll)pl * sQp + kt2 * 32);
    }

    f32x4 S[32];
    #pragma unroll
    for (int kv = 0; kv < 8; ++kv) {
        const u16* gk = qkvp + (size_t)(b * SS + kv * 64 + srow) * (3 * DD) + DD + h * HD + (ll)spl * sQp;
        #pragma unroll
        for (int qq = 0; qq < 4; ++qq) {
            int off = shalf * 32 + qq * 8;
            *(uint4*)&KV[spl][srow][off] = *(const uint4*)(gk + off);
        }
        __syncthreads();
        __builtin_amdgcn_s_setprio(1);
        #pragma unroll
        for (int nf = 0; nf < 4; ++nf) {
            f32x4 a0 = {}, a1 = {};
            #pragma unroll
            for (int kt2 = 0; kt2 < 2; ++kt2) {
                f16x8 b0 = *(const f16x8*)&KV[0][nf * 16 + (lane & 15)][kt2 * 32 + (lane >> 4) * 8];
                f16x8 b1 = *(const f16x8*)&KV[1][nf * 16 + (lane & 15)][kt2 * 32 + (lane >> 4) * 8];
                a0 = MFMA16(qf[kt2][0], b0, a0);
                a1 = MFMA16(qf[kt2][0], b1, a1);
                a1 = MFMA16(qf[kt2][1], b0, a1);
            }
            int col = kv * 64 + nf * 16 + (lane & 15);
            bool msk = pad[b * SS + col] != 0;
            #pragma unroll
            for (int r = 0; r < 4; ++r) {
                float v = (a0[r] + a1[r] * (1.0f / 4096.0f)) * 0.125f;
                S[kv * 4 + nf][r] = msk ? -1e9f : v;
            }
        }
        __builtin_amdgcn_s_setprio(0);
        __syncthreads();
    }

    float mx[4] = {-1e30f, -1e30f, -1e30f, -1e30f}, sm[4] = {0.f, 0.f, 0.f, 0.f}, inv[4];
    #pragma unroll
    for (int f = 0; f < 32; ++f)
        #pragma unroll
        for (int r = 0; r < 4; ++r) mx[r] = fmaxf(mx[r], S[f][r]);
    #pragma unroll
    for (int r = 0; r < 4; ++r) {
        #pragma unroll
        for (int off = 1; off < 16; off <<= 1) mx[r] = fmaxf(mx[r], __shfl_xor(mx[r], off));
    }
    #pragma unroll
    for (int f = 0; f < 32; ++f)
        #pragma unroll
        for (int r = 0; r < 4; ++r) { float e = expf(S[f][r] - mx[r]); S[f][r] = e; sm[r] += e; }
    #pragma unroll
    for (int r = 0; r < 4; ++r) {
        #pragma unroll
        for (int off = 1; off < 16; off <<= 1) sm[r] += __shfl_xor(sm[r], off);
        inv[r] = 1.f / sm[r];
    }

    f32x4 p0[4] = {}, p1[4] = {};
    #pragma unroll
    for (int kv = 0; kv < 8; ++kv) {
        const u16* gv = vTp + (size_t)bh * HD * SS + (size_t)srow * SS + kv * 64 + (ll)spl * sVp;
        #pragma unroll
        for (int qq = 0; qq < 4; ++qq) {
            int off = shalf * 32 + qq * 8;
            *(uint4*)&KV[spl][srow][off] = *(const uint4*)(gv + off);
        }
        #pragma unroll
        for (int nf = 0; nf < 4; ++nf)
            #pragma unroll
            for (int r = 0; r < 4; ++r) {
                float v = S[kv * 4 + nf][r] * inv[r];
                u16 h0, h1; split2h(v, h0, h1);
                Pl[0][wv][(lane >> 4) * 4 + r][nf * 16 + (lane & 15)] = h0;
                Pl[1][wv][(lane >> 4) * 4 + r][nf * 16 + (lane & 15)] = h1;
            }
        __syncthreads();
        f16x8 pa[2][2];
        #pragma unroll
        for (int kt2 = 0; kt2 < 2; ++kt2)
            #pragma unroll
            for (int pl = 0; pl < 2; ++pl)
                pa[kt2][pl] = *(const f16x8*)&Pl[pl][wv][lane & 15][kt2 * 32 + (lane >> 4) * 8];
        __builtin_amdgcn_s_setprio(1);
        #pragma unroll
        for (int df = 0; df < 4; ++df) {
            #pragma unroll
            for (int kt2 = 0; kt2 < 2; ++kt2) {
                f16x8 v0 = *(const f16x8*)&KV[0][df * 16 + (lane & 15)][kt2 * 32 + (lane >> 4) * 8];
                f16x8 v1 = *(const f16x8*)&KV[1][df * 16 + (lane & 15)][kt2 * 32 + (lane >> 4) * 8];
                p0[df] = MFMA16(pa[kt2][0], v0, p0[df]);
                p1[df] = MFMA16(pa[kt2][0], v1, p1[df]);
                p1[df] = MFMA16(pa[kt2][1], v0, p1[df]);
            }
        }
        __builtin_amdgcn_s_setprio(0);
        __syncthreads();
    }

    #pragma unroll
    for (int df = 0; df < 4; ++df)
        #pragma unroll
        for (int r = 0; r < 4; ++r) {
            float v = p0[df][r] + p1[df][r] * (1.0f / 4096.0f);
            int row = qbase + (lane >> 4) * 4 + r;
            int col = h * HD + df * 16 + (lane & 15);
            u16 h0, h1; split2h(v, h0, h1);
            attnp[(size_t)row * DD + col] = h0;
            attnp[(size_t)row * DD + col + sOp] = h1;
        }
}

// ---------------- split-K reduce ----------------
struct RedP {
    const float* part = nullptr; ll partStride = 0; int KS = 1;
    float* outf = nullptr;
    u16* o0 = nullptr; ll planeStride = 0;
    const float* bias = nullptr; ll biasStride = 0; ll batchElems = 1; int Nc = 1;
    const float* src = nullptr;
    ll total = 0; int mode = 0;   // 1=bias 2=relu 4=src 8=planes-out
};
__global__ void reduce_kernel(RedP p) {
    ll e0 = ((ll)blockIdx.x * 256 + threadIdx.x) * 4;
    if (e0 >= p.total) return;
    float4 s = *(const float4*)(p.part + e0);
    for (int k = 1; k < p.KS; ++k) {
        float4 t = *(const float4*)(p.part + (ll)k * p.partStride + e0);
        s.x += t.x; s.y += t.y; s.z += t.z; s.w += t.w;
    }
    if (p.mode & 1) {
        ll b = e0 / p.batchElems;
        int d = (int)(e0 % p.Nc);
        float4 bv = *(const float4*)(p.bias + b * p.biasStride + d);
        s.x = __fadd_rn(s.x, bv.x); s.y = __fadd_rn(s.y, bv.y);
        s.z = __fadd_rn(s.z, bv.z); s.w = __fadd_rn(s.w, bv.w);
    }
    if (p.mode & 4) {
        float4 t = *(const float4*)(p.src + e0);
        s.x = __fadd_rn(s.x, t.x); s.y = __fadd_rn(s.y, t.y);
        s.z = __fadd_rn(s.z, t.z); s.w = __fadd_rn(s.w, t.w);
    }
    if (p.mode & 2) { s.x = fmaxf(s.x, 0.f); s.y = fmaxf(s.y, 0.f); s.z = fmaxf(s.z, 0.f); s.w = fmaxf(s.w, 0.f); }
    if (p.mode & 8) {
        u16 t0[4], t1[4];
        float vv[4] = {s.x, s.y, s.z, s.w};
        #pragma unroll
        for (int e = 0; e < 4; ++e) split2h(vv[e], t0[e], t1[e]);
        *(uint2*)(p.o0 + e0) = *(uint2*)t0;
        *(uint2*)(p.o0 + p.planeStride + e0) = *(uint2*)t1;
    } else {
        *(float4*)(p.outf + e0) = s;
    }
}

// ---------------- weight split prepass ----------------
__global__ void wsplit_kernel(const float* __restrict__ w, u16* __restrict__ p0,
                              ll planeStride, ll total) {
    ll e0 = ((ll)blockIdx.x * 256 + threadIdx.x) * 4;
    if (e0 >= total) return;
    float4 v = *(const float4*)(w + e0);
    u16 t0[4], t1[4];
    float vv[4] = {v.x, v.y, v.z, v.w};
    #pragma unroll
    for (int e = 0; e < 4; ++e) split2h(vv[e], t0[e], t1[e]);
    *(uint2*)(p0 + e0) = *(uint2*)t0;
    *(uint2*)(p0 + planeStride + e0) = *(uint2*)t1;
}

// ---------------- V transpose ----------------
__global__ void vtrans_kernel(const u16* __restrict__ qkvp, ll sQp,
                              u16* __restrict__ vTp, ll sVp) {
    __shared__ float t[32][33];
    int z = blockIdx.z;
    int b = z / HH, h = z % HH;
    int c0 = blockIdx.x * 32, r0 = blockIdx.y * 32;
    int tx = threadIdx.x, ty = threadIdx.y;
    const u16* in = qkvp + (size_t)(b * SS) * (3 * DD) + 2 * DD + h * HD;
    #pragma unroll
    for (int i = 0; i < 32; i += 8) {
        size_t o = (size_t)(r0 + ty + i) * (3 * DD) + c0 + tx;
        t[ty + i][tx] = rec2h(in[o], in[o + sQp]);
    }
    __syncthreads();
    u16* out = vTp + (size_t)z * HD * SS;
    #pragma unroll
    for (int i = 0; i < 32; i += 8) {
        size_t o = (size_t)(c0 + ty + i) * SS + r0 + tx;
        u16 h0, h1; split2h(t[tx][ty + i], h0, h1);
        out[o] = h0; out[o + sVp] = h1;
    }
}

// ---------------- pe table (numpy f32 chain) ----------------
__global__ void pe_kernel(float* __restrict__ pe) {
    int s = blockIdx.x, tid = threadIdx.x;
    const float lg = 9.210340371976184f;
    #pragma unroll
    for (int j = 0; j < 3; ++j) {
        int d = j * 256 + tid;
        int half = d >> 1;
        float fi = (float)(2 * half) / 768.0f;
        float arg = __fmul_rn(-fi, lg);
        float freq = (float)exp((double)arg);
        float ang = __fmul_rn((float)s, freq);
        double da = (double)ang;
        pe[(size_t)s * DD + d] = (d & 1) ? (float)cos(da) : (float)sin(da);
    }
}

__global__ void embed_kernel(const int* __restrict__ src, const float* __restrict__ emb,
                             const float* __restrict__ pe, float* __restrict__ x) {
    int t = blockIdx.x, tid = threadIdx.x;
    int s = t & (SS - 1);
    int tok = src[t];
    const float sq = 27.712812921102035f;
    #pragma unroll
    for (int j = 0; j < 3; ++j) {
        int d = j * 256 + tid;
        float e = emb[(size_t)tok * DD + d];
        x[(size_t)t * DD + d] = __fadd_rn(__fmul_rn(e, sq), pe[(size_t)s * DD + d]);
    }
}

// ---------------- layernorm (op nullable) ----------------
__global__ void ln_kernel(const float* __restrict__ x, const float* __restrict__ g,
                          const float* __restrict__ b, float* __restrict__ outf,
                          u16* __restrict__ op, ll planeStride) {
    int t = blockIdx.x, tid = threadIdx.x;
    const float* xr = x + (size_t)t * DD;
    float v[3], s = 0.f, sq = 0.f;
    #pragma unroll
    for (int j = 0; j < 3; ++j) { v[j] = xr[tid + j * 256]; s += v[j]; sq += v[j] * v[j]; }
    #pragma unroll
    for (int off = 32; off; off >>= 1) { s += __shfl_xor(s, off); sq += __shfl_xor(sq, off); }
    __shared__ float rs[4], rq[4];
    int wid = tid >> 6;
    if ((tid & 63) == 0) { rs[wid] = s; rq[wid] = sq; }
    __syncthreads();
    s = rs[0] + rs[1] + rs[2] + rs[3];
    sq = rq[0] + rq[1] + rq[2] + rq[3];
    float mu = s / 768.0f;
    float var = sq / 768.0f - mu * mu;
    float rstd = rsqrtf(var + 1e-5f);
    #pragma unroll
    for (int j = 0; j < 3; ++j) {
        int d = tid + j * 256;
        float y = __fadd_rn(__fmul_rn(__fmul_rn(v[j] - mu, rstd), g[d]), b[d]);
        if (outf) outf[(size_t)t * DD + d] = y;
        if (op) {
            size_t o = (size_t)t * DD + d;
            u16 h0, h1; split2h(y, h0, h1);
            op[o] = h0; op[o + planeStride] = h1;
        }
    }
}

// ---------------- fused LN2 + router ----------------
__global__ void ln2_router_kernel(const float* __restrict__ x, const float* __restrict__ g,
                                  const float* __restrict__ b, const float* __restrict__ wr,
                                  const unsigned char* __restrict__ pad,
                                  u16* __restrict__ op, ll planeStride,
                                  float* __restrict__ probs, float* __restrict__ lsev,
                                  float* __restrict__ gate, int* __restrict__ idx) {
    int t = blockIdx.x, tid = threadIdx.x;
    const float* xr = x + (size_t)t * DD;
    float v[3], s = 0.f, sq = 0.f;
    #pragma unroll
    for (int j = 0; j < 3; ++j) { v[j] = xr[tid + j * 256]; s += v[j]; sq += v[j] * v[j]; }
    #pragma unroll
    for (int off = 32; off; off >>= 1) { s += __shfl_xor(s, off); sq += __shfl_xor(sq, off); }
    __shared__ float rs[4], rq[4];
    __shared__ float ra[4][8];
    int wid = tid >> 6;
    if ((tid & 63) == 0) { rs[wid] = s; rq[wid] = sq; }
    __syncthreads();
    s = rs[0] + rs[1] + rs[2] + rs[3];
    sq = rq[0] + rq[1] + rq[2] + rq[3];
    float mu = s / 768.0f;
    float var = sq / 768.0f - mu * mu;
    float rstd = rsqrtf(var + 1e-5f);
    float a[8] = {0.f, 0.f, 0.f, 0.f, 0.f, 0.f, 0.f, 0.f};
    #pragma unroll
    for (int j = 0; j < 3; ++j) {
        int d = tid + j * 256;
        float y = __fadd_rn(__fmul_rn(__fmul_rn(v[j] - mu, rstd), g[d]), b[d]);
        size_t o = (size_t)t * DD + d;
        u16 h0, h1; split2h(y, h0, h1);
        op[o] = h0; op[o + planeStride] = h1;
        const float* w = wr + (size_t)d * EE;
        #pragma unroll
        for (int e = 0; e < 8; ++e) a[e] += y * w[e];
    }
    #pragma unroll
    for (int off = 32; off; off >>= 1)
        #pragma unroll
        for (int e = 0; e < 8; ++e) a[e] += __shfl_xor(a[e], off);
    if ((tid & 63) == 0)
        #pragma unroll
        for (int e = 0; e < 8; ++e) ra[wid][e] = a[e];
    __syncthreads();
    if (tid == 0) {
        #pragma unroll
        for (int e = 0; e < 8; ++e) a[e] = ra[0][e] + ra[1][e] + ra[2][e] + ra[3][e];
        int vm = (pad[t] == 0);
        float mx = a[0]; int bi = 0;
        #pragma unroll
        for (int e = 1; e < 8; ++e) if (a[e] > mx) { mx = a[e]; bi = e; }
        float ex[8], sum = 0.f;
        #pragma unroll
        for (int e = 0; e < 8; ++e) { ex[e] = expf(a[e] - mx); sum += ex[e]; }
        float inv = 1.f / sum;
        #pragma unroll
        for (int e = 0; e < 8; ++e) probs[(size_t)t * EE + e] = vm ? ex[e] * inv : 0.f;
        lsev[t] = vm ? (mx + logf(sum)) : 0.f;
        gate[t] = ex[bi] * inv;
        idx[t] = vm ? bi : -1;
    }
}

// ---------------- routing scan ----------------
__global__ void route_scan_kernel(const int* __restrict__ idx, const float* __restrict__ probs,
                                  const float* __restrict__ lsev, int* __restrict__ slot,
                                  int* __restrict__ tos, float* __restrict__ acc) {
    int lane = threadIdx.x;
    int base = lane * 32;
    int ev[32];
    int c[8] = {0, 0, 0, 0, 0, 0, 0, 0};
    #pragma unroll
    for (int i = 0; i < 32; ++i) {
        int e = idx[base + i];
        ev[i] = e;
        #pragma unroll
        for (int q = 0; q < 8; ++q) c[q] += (e == q);
    }
    int excl[8], tot[8];
    #pragma unroll
    for (int e = 0; e < 8; ++e) {
        int v = c[e];
        #pragma unroll
        for (int off = 1; off < 64; off <<= 1) {
            int n = __shfl_up(v, off);
            if (lane >= off) v += n;
        }
        excl[e] = v - c[e];
        tot[e] = __shfl(v, 63);
    }
    int r[8];
    #pragma unroll
    for (int e = 0; e < 8; ++e) r[e] = excl[e];
    #pragma unroll
    for (int i = 0; i < 32; ++i) {
        int t = base + i, e = ev[i], s = -1;
        if (e >= 0) {
            int pos = 0;
            #pragma unroll
            for (int q = 0; q < 8; ++q) if (e == q) { r[q]++; pos = r[q]; }
            if (pos <= CAP) { s = e * CAP + pos - 1; tos[s] = t; }
        }
        slot[t] = s;
    }
    float pa[8] = {0.f, 0.f, 0.f, 0.f, 0.f, 0.f, 0.f, 0.f};
    float l2 = 0.f, vld = 0.f;
    #pragma unroll
    for (int i = 0; i < 32; ++i) {
        int t = base + i;
        float lv = lsev[t];
        l2 += lv * lv;
        if (ev[i] >= 0) vld += 1.f;
        #pragma unroll
        for (int e = 0; e < 8; ++e) pa[e] += probs[(size_t)t * EE + e];
    }
    #pragma unroll
    for (int off = 32; off; off >>= 1) {
        #pragma unroll
        for (int e = 0; e < 8; ++e) pa[e] += __shfl_xor(pa[e], off);
        l2 += __shfl_xor(l2, off);
        vld += __shfl_xor(vld, off);
    }
    if (lane == 0) {
        float denom = fmaxf(vld, 1.f);
        float lb = 0.f;
        #pragma unroll
        for (int e = 0; e < 8; ++e) lb += (pa[e] / denom) * ((float)tot[e] / denom);
        lb *= 8.f;
        acc[0] += lb;
        acc[1] += l2 / denom;
    }
}

// ---------------- gather ----------------
__global__ void gather_kernel(const int* __restrict__ tos, const u16* __restrict__ xnp,
                              ll sXp, u16* __restrict__ einp, ll sEp) {
    int s = blockIdx.x;
    int tid = threadIdx.x;
    if (tid >= 192) return;
    int pl = tid / 96, q = tid % 96;
    int t = tos[s];
    uint4 v = {0u, 0u, 0u, 0u};
    if (t >= 0) v = *(const uint4*)(xnp + (ll)pl * sXp + (size_t)t * DD + q * 8);
    *(uint4*)(einp + (ll)pl * sEp + (size_t)s * DD + q * 8) = v;
}

// ---------------- fused FFN2-reduce + combine ----------------
__global__ void combine2_kernel(const int* __restrict__ slot, const float* __restrict__ gate,
                                const float* __restrict__ part, ll partStride, int KS,
                                const float* __restrict__ b2, float* __restrict__ x) {
    int t = blockIdx.x, tid = threadIdx.x;
    int s = slot[t];
    if (s < 0) return;
    float gv = gate[t];
    int e = s / CAP;
    #pragma unroll
    for (int j = 0; j < 3; ++j) {
        int d = j * 256 + tid;
        size_t o = (size_t)s * DD + d;
        float v = part[o];
        for (int k = 1; k < KS; ++k) v += part[(ll)k * partStride + o];
        v = __fadd_rn(v, b2[(size_t)e * DD + d]);
        size_t ox = (size_t)t * DD + d;
        x[ox] = __fadd_rn(x[ox], __fmul_rn(gv, v));
    }
}

__global__ void finalize_kernel(const float* __restrict__ acc, float* __restrict__ out) {
    out[(size_t)TT * DD] = acc[0] * (1.f / NLAYER);
    out[(size_t)TT * DD + 1] = acc[1] * (1.f / NLAYER);
}

// ---------------- host ----------------
static inline void run_gemm(bool btrans, int ns, const GemmP& p, dim3 grid, hipStream_t s) {
    if (btrans) {
        if (ns == 2) gemm_kernel<true, 2><<<grid, 256, 0, s>>>(p);
        else gemm_kernel<true, 1><<<grid, 256, 0, s>>>(p);
    } else {
        if (ns == 2) gemm_kernel<false, 2><<<grid, 256, 0, s>>>(p);
        else gemm_kernel<false, 1><<<grid, 256, 0, s>>>(p);
    }
}
static inline void run_reduce(const RedP& r, hipStream_t s) {
    reduce_kernel<<<(int)((r.total / 4 + 255) / 256), 256, 0, s>>>(r);
}

extern "C" void kernel_launch(void* const* d_in, const int* in_sizes, int n_in,
                              void* d_out, int out_size, void* d_ws, size_t ws_size,
                              hipStream_t stream) {
    const int* src = (const int*)d_in[0];
    const unsigned char* pad = (const unsigned char*)d_in[1];
    const float* emb = (const float*)d_in[2];
    const float* qkv_w = (const float*)d_in[3];
    const float* qkv_b = (const float*)d_in[4];
    const float* out_w = (const float*)d_in[5];
    const float* out_b = (const float*)d_in[6];
    const float* wr = (const float*)d_in[7];
    const float* w1 = (const float*)d_in[8];
    const float* b1 = (const float*)d_in[9];
    const float* w2 = (const float*)d_in[10];
    const float* b2 = (const float*)d_in[11];
    const float* ln1_g = (const float*)d_in[12];
    const float* ln1_b = (const float*)d_in[13];
    const float* ln2_g = (const float*)d_in[14];
    const float* ln2_b = (const float*)d_in[15];
    const float* lnf_g = (const float*)d_in[16];
    const float* lnf_b = (const float*)d_in[17];

    char* w = (char*)d_ws;
    size_t off = 0;
    auto alloc = [&](size_t bytes) -> void* {
        void* p = w + off;
        off += (bytes + 255) & ~(size_t)255;
        return p;
    };
    float* x      = (float*)alloc((size_t)TT * DD * 4);
    float* peT    = (float*)alloc((size_t)SS * DD * 4);
    u16*   xnp    = (u16*)  alloc((size_t)2 * TT * DD * 2);
    u16*   qkvp   = (u16*)  alloc((size_t)2 * TT * 3 * DD * 2);
    u16*   vTp    = (u16*)  alloc((size_t)2 * BB * HH * HD * SS * 2);
    u16*   attnp  = (u16*)  alloc((size_t)2 * TT * DD * 2);
    u16*   einp   = (u16*)  alloc((size_t)2 * EE * CAP * DD * 2);
    u16*   hidp   = (u16*)  alloc((size_t)2 * EE * CAP * DFF * 2);
    char*  regB   = (char*) alloc((size_t)2 * TT * 3 * DD * 4);      // partials (max: qkv KS2)
    u16*   qkvwp  = (u16*)  alloc((size_t)2 * NLAYER * 3 * DD * DD * 2);
    u16*   owp    = (u16*)  alloc((size_t)2 * NLAYER * DD * DD * 2);
    float* probs  = (float*)alloc((size_t)TT * EE * 4);
    float* lsev   = (float*)alloc((size_t)TT * 4);
    float* gate   = (float*)alloc((size_t)TT * 4);
    int*   idx    = (int*)  alloc((size_t)TT * 4);
    int*   slot   = (int*)  alloc((size_t)TT * 4);
    int*   tos    = (int*)  alloc((size_t)EE * CAP * 4);
    float* accb   = (float*)alloc(256);
    if (off > ws_size) return;

    float* qkvpart = (float*)regB;   // KS2 x TT*3DD = 37.7MB
    float* oppart  = (float*)regB;   // KS4 x TT*DD  = 25.2MB
    float* ffnpart = (float*)regB;   // KS4 x E*CAP*DD = 31.5MB

    hipMemsetAsync(accb, 0, 8, stream);
    pe_kernel<<<SS, 256, 0, stream>>>(peT);
    embed_kernel<<<TT, 256, 0, stream>>>(src, emb, peT, x);

    {
        ll tq = (ll)NLAYER * 3 * DD * DD;
        wsplit_kernel<<<(int)((tq / 4 + 255) / 256), 256, 0, stream>>>(qkv_w, qkvwp, tq, tq);
        ll to = (ll)NLAYER * DD * DD;
        wsplit_kernel<<<(int)((to / 4 + 255) / 256), 256, 0, stream>>>(out_w, owp, to, to);
    }

    for (int l = 0; l < NLAYER; ++l) {
        const int nsF = (l < NLAYER - 1) ? 2 : 1;
        ln_kernel<<<TT, 256, 0, stream>>>(x, ln1_g + l * DD, ln1_b + l * DD, nullptr, xnp, (ll)TT * DD);

        // QKV (KS=2): kslice 384 = 6 k-iters
        {
            GemmP p;
            p.A = xnp; p.sAp = (ll)TT * DD; p.lda = DD;
            p.B = qkvwp + (size_t)l * 3 * DD * DD; p.sBp = (ll)NLAYER * 3 * DD * DD; p.ldb = DD;
            p.C = qkvpart; p.ldc = 3 * DD;
            p.M = TT; p.N = 3 * DD; p.K = DD;
            p.flags = 16; p.KS = 2; p.partStride = (ll)TT * 3 * DD;
            p.Jc = 4;
            run_gemm(true, 2, p, dim3(18, 16, 2), stream);
        }
        {
            RedP r;
            r.part = qkvpart; r.partStride = (ll)TT * 3 * DD; r.KS = 2;
            r.o0 = qkvp; r.planeStride = (ll)TT * 3 * DD;
            r.bias = qkv_b + (size_t)l * 3 * DD; r.biasStride = 0; r.batchElems = (ll)TT * 3 * DD; r.Nc = 3 * DD;
            r.total = (ll)TT * 3 * DD; r.mode = 1 | 8;
            run_reduce(r, stream);
        }
        vtrans_kernel<<<dim3(HD / 32, SS / 32, BB * HH), dim3(32, 8), 0, stream>>>(
            qkvp, (ll)TT * 3 * DD, vTp, (ll)BB * HH * HD * SS);
        flash_kernel<<<BB * HH * 8, 256, 0, stream>>>(
            qkvp, (ll)TT * 3 * DD, vTp, (ll)BB * HH * HD * SS, pad, attnp, (ll)TT * DD);
        // out-proj (KS=4): kslice 192 = 3 k-iters; reduce adds bias + residual
        {
            GemmP p;
            p.A = attnp; p.sAp = (ll)TT * DD; p.lda = DD;
            p.B = owp + (size_t)l * DD * DD; p.sBp = (ll)NLAYER * DD * DD; p.ldb = DD;
            p.C = oppart; p.ldc = DD;
            p.M = TT; p.N = DD; p.K = DD;
            p.flags = 16; p.KS = 4; p.partStride = (ll)TT * DD;
            p.Jc = 8;
            run_gemm(true, 2, p, dim3(6, 16, 4), stream);
        }
        {
            RedP r;
            r.part = oppart; r.partStride = (ll)TT * DD; r.KS = 4;
            r.outf = x;
            r.bias = out_b + (size_t)l * DD; r.biasStride = 0; r.batchElems = (ll)TT * DD; r.Nc = DD;
            r.src = x;
            r.total = (ll)TT * DD; r.mode = 1 | 4;
            run_reduce(r, stream);
        }
        // fused LN2 + router
        ln2_router_kernel<<<TT, 256, 0, stream>>>(x, ln2_g + l * DD, ln2_b + l * DD,
                                                  wr + (size_t)l * DD * EE, pad,
                                                  xnp, (ll)TT * DD, probs, lsev, gate, idx);
        hipMemsetAsync(tos, 0xFF, (size_t)EE * CAP * 4, stream);
        route_scan_kernel<<<1, 64, 0, stream>>>(idx, probs, lsev, slot, tos, accb);
        gather_kernel<<<EE * CAP, 256, 0, stream>>>(tos, xnp, (ll)TT * DD, einp, (ll)EE * CAP * DD);
        // FFN1 (KS=1, direct planes-out with bias+relu): 12 k-iters, 576 blocks
        {
            GemmP p;
            p.A = einp; p.sAp = (ll)EE * CAP * DD; p.lda = DD;
            p.modA = EE; p.sA1 = (ll)CAP * DD;
            p.B = w1 + (size_t)l * EE * DD * DFF; p.ldb = DFF;
            p.modB = EE; p.sB1 = (ll)DD * DFF;
            p.bias = b1 + (size_t)l * EE * DFF; p.biasStride = DFF;
            p.C = hidp; p.sCp = (ll)EE * CAP * DFF; p.ldc = DFF;
            p.modC = EE; p.sC1 = (ll)CAP * DFF;
            p.M = CAP; p.N = DFF; p.K = DD;
            p.flags = 1 | 2 | 8;
            p.Jc = 3;
            run_gemm(false, nsF, p, dim3(24, 3, EE), stream);
        }
        // FFN2 (KS=4): kslice 768 = 12 k-iters; combine2 sums partials + b2 into x
        {
            GemmP p;
            p.A = hidp; p.sAp = (ll)EE * CAP * DFF; p.lda = DFF;
            p.modA = EE; p.sA1 = (ll)CAP * DFF;
            p.B = w2 + (size_t)l * EE * DFF * DD; p.ldb = DD;
            p.modB = EE; p.sB1 = (ll)DFF * DD;
            p.C = ffnpart; p.ldc = DD; p.modC = EE; p.sC1 = (ll)CAP * DD;
            p.M = CAP; p.N = DD; p.K = DFF;
            p.flags = 16; p.KS = 4; p.partStride = (ll)EE * CAP * DD;
            p.Jc = 12;
            run_gemm(false, nsF, p, dim3(6, 3, EE * 4), stream);
        }
        combine2_kernel<<<TT, 256, 0, stream>>>(slot, gate, ffnpart, (ll)EE * CAP * DD, 4,
                                                b2 + (size_t)l * EE * DD, x);
    }
    ln_kernel<<<TT, 256, 0, stream>>>(x, lnf_g, lnf_b, (float*)d_out, nullptr, 0);
    finalize_kernel<<<1, 1, 0, stream>>>(accb, (float*)d_out);
}